// Round 3
// baseline (31201.910 us; speedup 1.0000x reference)
//
#include <hip/hip_runtime.h>

// RNN: h_t = tanh(E[x_t] + h_{t-1} @ Whh + bh), T=1024, N=64, H=1024.
// y = softmax(z @ Wout + bout). Output: y (64*1024*256 f32) then h_last (64*1024 f32).
//
// Recurrence runs in DOUBLE-FP16 (hi + 2^-11*lo splits of both h and Whh, lo
// planes pre-scaled by 2048) -> ~fp32-equivalent per-step precision, needed
// because the tanh recurrence chaotically amplifies fp16 noise ~1000x over
// 1024 steps (Round-0 evidence: y passed, h_last absmax 0.648).
// 64 persistent WGs, each owns 16 h-columns; Whh^T hi/lo fragments resident in
// 256 VGPRs. Cross-WG h exchange: hi/lo fp16 planes ping-pong in ws, per-step
// flags w/ acquire-release + threadfence. Output GEMM+softmax: separate MFMA
// kernel over stored z (fp16 — proven loose enough by R0).

typedef _Float16 f16x8 __attribute__((ext_vector_type(8)));
typedef float    f32x4 __attribute__((ext_vector_type(4)));

#define NSEQ  64
#define TSEQ  1024
#define HDIM  1024
#define VOCABSZ 256
#define ODIM  256
#define NWG   64     // one WG per 16 columns of H
#define LOSCALE 2048.0f
#define LOINV  (1.0f/2048.0f)

// ---------------------------------------------------------------- init / prep
__global__ __launch_bounds__(256) void rnn_init(
    const float* __restrict__ Whh, const float* __restrict__ Wout,
    _Float16* __restrict__ whhT_hi, _Float16* __restrict__ whhT_lo,
    _Float16* __restrict__ woutT,
    _Float16* __restrict__ hbuf, unsigned* __restrict__ flags)
{
    int i = blockIdx.x * 256 + threadIdx.x;
    int stride = gridDim.x * 256;
    // Whh^T split: whhT_*[j][k] from Whh[k][j]
    for (int idx = i; idx < HDIM * HDIM; idx += stride) {
        int j = idx >> 10, k = idx & 1023;
        float w = Whh[k * HDIM + j];
        _Float16 hi = (_Float16)w;
        whhT_hi[idx] = hi;
        whhT_lo[idx] = (_Float16)((w - (float)hi) * LOSCALE);
    }
    // Wout^T fp16
    for (int idx = i; idx < ODIM * HDIM; idx += stride) {
        int o = idx >> 10, k = idx & 1023;
        woutT[idx] = (_Float16)Wout[k * ODIM + o];
    }
    // zero both ping-pong buffers, both hi/lo planes (h0 = 0)
    for (int idx = i; idx < 4 * NSEQ * HDIM; idx += stride) hbuf[idx] = (_Float16)0.f;
    for (int idx = i; idx < TSEQ * NWG; idx += stride) flags[idx] = 0u;
}

// ---------------------------------------------------------------- recurrence
// hbuf layout: [buf(2)][plane(2: hi,lo)][NSEQ][HDIM] fp16
#define HPLANE (NSEQ * HDIM)
#define HBUFSZ (2 * HPLANE)

__global__ __launch_bounds__(256, 1) void rnn_steps(
    const int*   __restrict__ x,       // [NSEQ][TSEQ]
    const float* __restrict__ E,       // [VOCAB][HDIM]
    const float* __restrict__ bh,      // [HDIM]
    const _Float16* __restrict__ whhT_hi, // [HDIM][HDIM] j-major
    const _Float16* __restrict__ whhT_lo,
    _Float16* __restrict__ hbuf,
    unsigned* __restrict__ flags,      // [TSEQ][NWG]
    _Float16* __restrict__ z,          // chunk: [tc][NSEQ*HDIM]
    float* __restrict__ hlast_out,     // [NSEQ*HDIM]
    int t0, int t1)
{
    const int c   = blockIdx.x;        // column-group 0..63
    const int j0  = c * 16;
    const int tid = threadIdx.x;
    const int lane = tid & 63;
    const int wv   = tid >> 6;         // wave 0..3 -> seq rows n0..n0+15
    const int n0   = wv * 16;
    const int lr   = lane & 15;        // fragment row/col selector
    const int lq   = lane >> 4;        // k-chunk selector (0..3)

    __shared__ float e_s[VOCABSZ][16]; // E slice for our 16 columns
    __shared__ float bh_s[16];

    {   // stage E[:, j0:j0+16]
        const float* src = E + (size_t)tid * HDIM + j0;
        #pragma unroll
        for (int jj = 0; jj < 16; ++jj) e_s[tid][jj] = src[jj];
        if (tid < 16) bh_s[tid] = bh[j0 + tid];
    }

    // Resident B-fragments: hi + scaled-lo, 64 x f16x8 = 256 VGPRs
    f16x8 bf_hi[32], bf_lo[32];
    {
        const size_t boff = (size_t)(j0 + lr) * HDIM + lq * 8;
        #pragma unroll
        for (int m = 0; m < 32; ++m) {
            bf_hi[m] = *(const f16x8*)(whhT_hi + boff + m * 32);
            bf_lo[m] = *(const f16x8*)(whhT_lo + boff + m * 32);
        }
    }
    __syncthreads();

    for (int t = t0; t < t1; ++t) {
        if (t > 0) {
            // wait for all 64 producers of h_t (step t-1)
            unsigned* f = flags + (size_t)(t - 1) * NWG;
            while (!__all((int)(__hip_atomic_load(&f[lane], __ATOMIC_ACQUIRE,
                                                  __HIP_MEMORY_SCOPE_AGENT) != 0u)))
                __builtin_amdgcn_s_sleep(2);
            __threadfence();   // acquire: make h stores visible
        }
        const _Float16* hin_hi  = hbuf + (size_t)( t      & 1) * HBUFSZ;
        const _Float16* hin_lo  = hin_hi + HPLANE;
        _Float16*       hout_hi = hbuf + (size_t)((t + 1) & 1) * HBUFSZ;
        _Float16*       hout_lo = hout_hi + HPLANE;

        // 16x16 tile (n0..+15) x (j0..+15), K=1024, double-fp16:
        //   acc0 = sum a_hi*b_hi ; acc1 = sum (a_lo_s*b_hi + a_hi*b_lo_s)
        //   result = acc0 + acc1 * 2^-11
        f32x4 acc0 = {0.f, 0.f, 0.f, 0.f};
        f32x4 acc1 = {0.f, 0.f, 0.f, 0.f};
        const size_t aoff = (size_t)(n0 + lr) * HDIM + lq * 8;
        #pragma unroll
        for (int m = 0; m < 32; ++m) {
            f16x8 a_hi = *(const f16x8*)(hin_hi + aoff + m * 32);
            f16x8 a_lo = *(const f16x8*)(hin_lo + aoff + m * 32);
            acc0 = __builtin_amdgcn_mfma_f32_16x16x32_f16(a_hi, bf_hi[m], acc0, 0, 0, 0);
            acc1 = __builtin_amdgcn_mfma_f32_16x16x32_f16(a_lo, bf_hi[m], acc1, 0, 0, 0);
            acc1 = __builtin_amdgcn_mfma_f32_16x16x32_f16(a_hi, bf_lo[m], acc1, 0, 0, 0);
        }

        // epilogue: D layout row=(lq*4+r), col=lr
        _Float16* zrow = z + (size_t)(t - t0) * (NSEQ * HDIM);
        #pragma unroll
        for (int r = 0; r < 4; ++r) {
            int n = n0 + lq * 4 + r;
            int j = j0 + lr;
            int tok = x[n * TSEQ + t];
            float pre = acc0[r] + acc1[r] * LOINV + e_s[tok][lr] + bh_s[lr];
            float hv  = tanhf(pre);
            _Float16 h16 = (_Float16)hv;
            _Float16 l16 = (_Float16)((hv - (float)h16) * LOSCALE);
            hout_hi[(size_t)n * HDIM + j] = h16;
            hout_lo[(size_t)n * HDIM + j] = l16;
            zrow[(size_t)n * HDIM + j] = h16;
            if (t == TSEQ - 1) hlast_out[(size_t)n * HDIM + j] = hv;
        }

        __threadfence();      // release: push h/z writes to device scope
        __syncthreads();      // all waves of this WG done
        if (tid == 0)
            __hip_atomic_store(&flags[(size_t)t * NWG + c], 1u,
                               __ATOMIC_RELEASE, __HIP_MEMORY_SCOPE_AGENT);
    }
}

// ---------------------------------------------------------------- output GEMM + softmax
__global__ __launch_bounds__(256, 1) void rnn_out(
    const _Float16* __restrict__ z,      // chunk: [tc][NSEQ*HDIM]
    const _Float16* __restrict__ woutT,  // [ODIM][HDIM]
    const float* __restrict__ bout,      // [ODIM]
    float* __restrict__ y,               // [NSEQ][TSEQ][ODIM]
    int t0, int tc)
{
    const int b = blockIdx.x;
    const int t_rel = b >> 2, ng = b & 3;
    const int t = t0 + t_rel;
    const int n0 = ng * 16;
    const int tid = threadIdx.x;
    const int lane = tid & 63, wv = tid >> 6;
    const int lr = lane & 15, lq = lane >> 4;

    __shared__ float lg[16][ODIM + 8];   // logits staging

    const _Float16* abase = z + (size_t)t_rel * (NSEQ * HDIM)
                              + (size_t)(n0 + lr) * HDIM + lq * 8;
    f16x8 af[32];
    #pragma unroll
    for (int m = 0; m < 32; ++m) af[m] = *(const f16x8*)(abase + m * 32);

    #pragma unroll
    for (int i = 0; i < 4; ++i) {
        int ot = (wv * 4 + i) * 16;
        const _Float16* bbase = woutT + (size_t)(ot + lr) * HDIM + lq * 8;
        f32x4 acc = {0.f, 0.f, 0.f, 0.f};
        #pragma unroll
        for (int m = 0; m < 32; ++m) {
            f16x8 bfr = *(const f16x8*)(bbase + m * 32);
            acc = __builtin_amdgcn_mfma_f32_16x16x32_f16(af[m], bfr, acc, 0, 0, 0);
        }
        #pragma unroll
        for (int r = 0; r < 4; ++r)
            lg[lq * 4 + r][ot + lr] = acc[r];
    }
    __syncthreads();

    for (int rr = 0; rr < 4; ++rr) {
        int row = wv * 4 + rr;
        int n = n0 + row;
        float v0 = lg[row][lane]       + bout[lane];
        float v1 = lg[row][64 + lane]  + bout[64 + lane];
        float v2 = lg[row][128 + lane] + bout[128 + lane];
        float v3 = lg[row][192 + lane] + bout[192 + lane];
        float mx = fmaxf(fmaxf(v0, v1), fmaxf(v2, v3));
        for (int s = 32; s > 0; s >>= 1) mx = fmaxf(mx, __shfl_xor(mx, s));
        float e0 = __expf(v0 - mx), e1 = __expf(v1 - mx);
        float e2 = __expf(v2 - mx), e3 = __expf(v3 - mx);
        float sm = e0 + e1 + e2 + e3;
        for (int s = 32; s > 0; s >>= 1) sm += __shfl_xor(sm, s);
        float inv = 1.f / sm;
        float* dst = y + ((size_t)n * TSEQ + t) * ODIM;
        dst[lane]       = e0 * inv;
        dst[64 + lane]  = e1 * inv;
        dst[128 + lane] = e2 * inv;
        dst[192 + lane] = e3 * inv;
    }
}

// ---------------------------------------------------------------- launch
extern "C" void kernel_launch(void* const* d_in, const int* in_sizes, int n_in,
                              void* d_out, int out_size, void* d_ws, size_t ws_size,
                              hipStream_t stream)
{
    const int*   x    = (const int*)  d_in[0];
    const float* E    = (const float*)d_in[1];
    const float* Whh  = (const float*)d_in[2];
    const float* bh   = (const float*)d_in[3];
    const float* Wout = (const float*)d_in[4];
    const float* bout = (const float*)d_in[5];

    float* y     = (float*)d_out;
    float* hlast = y + (size_t)NSEQ * TSEQ * ODIM;

    char* ws = (char*)d_ws;
    size_t off = 0;
    auto alloc = [&](size_t bytes) -> void* {
        void* p = ws + off;
        off = (off + bytes + 255) & ~(size_t)255;
        return p;
    };
    _Float16* whhT_hi = (_Float16*)alloc((size_t)HDIM * HDIM * 2);
    _Float16* whhT_lo = (_Float16*)alloc((size_t)HDIM * HDIM * 2);
    _Float16* woutT   = (_Float16*)alloc((size_t)ODIM * HDIM * 2);
    _Float16* hbuf    = (_Float16*)alloc((size_t)2 * HBUFSZ * 2);
    unsigned* flags   = (unsigned*)alloc((size_t)TSEQ * NWG * 4);
    _Float16* z       = (_Float16*)(ws + off);

    size_t zcap = (ws_size > off) ? (ws_size - off) : 0;
    int tc_max = (int)(zcap / ((size_t)NSEQ * HDIM * 2));
    if (tc_max > TSEQ) tc_max = TSEQ;
    if (tc_max < 1)    tc_max = 1;   // ws assumed >= ~8 MB

    rnn_init<<<2048, 256, 0, stream>>>(Whh, Wout, whhT_hi, whhT_lo, woutT,
                                       hbuf, flags);

    for (int t0 = 0; t0 < TSEQ; t0 += tc_max) {
        int tc = TSEQ - t0 < tc_max ? TSEQ - t0 : tc_max;
        rnn_steps<<<NWG, 256, 0, stream>>>(x, E, bh, whhT_hi, whhT_lo, hbuf,
                                           flags, z, hlast, t0, t0 + tc);
        rnn_out<<<tc * 4, 256, 0, stream>>>(z, woutT, bout, y, t0, tc);
    }
}

// Round 5
// 18138.139 us; speedup vs baseline: 1.7202x; 1.7202x over previous
//
#include <hip/hip_runtime.h>

// RNN: h_t = tanh(E[x_t] + h_{t-1} @ Whh + bh), T=1024, N=64, H=1024.
// y = softmax(z @ Wout + bout). Output: y (64*1024*256 f32) then h_last (64*1024 f32).
//
// Double-FP16 recurrence (hi + 2^-11*lo of h and Whh) for fp32-equivalent
// per-step precision (R3: passed, absmax 9.8e-4).
// R4 changes (R3 was 30us/step, sync-storm-bound):
//  - relaxed flag polls + ONE acquire fence per step (R2's per-poll ACQUIRE
//    emitted an L1+L2 invalidate per spin iteration -> L2 wreckage)
//  - h exchange stores bypass L1/L2 (global_store_short sc0 sc1 + vmcnt(0)),
//    so no wbl2 release fence is needed before the flag store
//  - Whh fragments pinned in VGPRs via asm "+v" (R3 compiler sank them back
//    to per-step global reloads: VGPR_Count was 156, not ~400)

typedef _Float16 f16x8 __attribute__((ext_vector_type(8)));
typedef float    f32x4 __attribute__((ext_vector_type(4)));

#define NSEQ  64
#define TSEQ  1024
#define HDIM  1024
#define VOCABSZ 256
#define ODIM  256
#define NWG   64     // one WG per 16 columns of H
#define LOSCALE 2048.0f
#define LOINV  (1.0f/2048.0f)

// hbuf layout: [buf(2)][plane(2: hi,lo)][NSEQ][HDIM] fp16
#define HPLANE (NSEQ * HDIM)
#define HBUFSZ (2 * HPLANE)

// ---------------------------------------------------------------- init / prep
__global__ __launch_bounds__(256) void rnn_init(
    const float* __restrict__ Whh, const float* __restrict__ Wout,
    _Float16* __restrict__ whhT_hi, _Float16* __restrict__ whhT_lo,
    _Float16* __restrict__ woutT,
    _Float16* __restrict__ hbuf, unsigned* __restrict__ flags)
{
    int i = blockIdx.x * 256 + threadIdx.x;
    int stride = gridDim.x * 256;
    for (int idx = i; idx < HDIM * HDIM; idx += stride) {
        int j = idx >> 10, k = idx & 1023;
        float w = Whh[k * HDIM + j];
        _Float16 hi = (_Float16)w;
        whhT_hi[idx] = hi;
        whhT_lo[idx] = (_Float16)((w - (float)hi) * LOSCALE);
    }
    for (int idx = i; idx < ODIM * HDIM; idx += stride) {
        int o = idx >> 10, k = idx & 1023;
        woutT[idx] = (_Float16)Wout[k * ODIM + o];
    }
    for (int idx = i; idx < 2 * HBUFSZ; idx += stride) hbuf[idx] = (_Float16)0.f;
    for (int idx = i; idx < TSEQ * NWG; idx += stride) flags[idx] = 0u;
}

// ---------------------------------------------------------------- recurrence
__global__ __launch_bounds__(256, 1) void rnn_steps(
    const int*   __restrict__ x,          // [NSEQ][TSEQ]
    const float* __restrict__ E,          // [VOCAB][HDIM]
    const float* __restrict__ bh,         // [HDIM]
    const _Float16* __restrict__ whhT_hi, // [HDIM][HDIM] j-major
    const _Float16* __restrict__ whhT_lo,
    _Float16* __restrict__ hbuf,
    unsigned* __restrict__ flags,         // [TSEQ][NWG]
    _Float16* __restrict__ z,             // chunk: [tc][NSEQ*HDIM]
    float* __restrict__ hlast_out,        // [NSEQ*HDIM]
    int t0, int t1)
{
    const int c   = blockIdx.x;        // column-group 0..63
    const int j0  = c * 16;
    const int tid = threadIdx.x;
    const int lane = tid & 63;
    const int wv   = tid >> 6;         // wave 0..3 -> seq rows n0..n0+15
    const int n0   = wv * 16;
    const int lr   = lane & 15;        // fragment row/col selector
    const int lq   = lane >> 4;        // k-chunk selector (0..3)

    __shared__ float e_s[VOCABSZ][16]; // (E + bh) slice for our 16 columns

    {   // stage E[:, j0:j0+16] + bh fold
        const float* src = E + (size_t)tid * HDIM + j0;
        #pragma unroll
        for (int jj = 0; jj < 16; ++jj) e_s[tid][jj] = src[jj] + bh[j0 + jj];
    }

    // Resident B-fragments: hi + scaled-lo, 64 x f16x8 = 256 VGPRs
    f16x8 bf_hi[32], bf_lo[32];
    {
        const size_t boff = (size_t)(j0 + lr) * HDIM + lq * 8;
        #pragma unroll
        for (int m = 0; m < 32; ++m) {
            bf_hi[m] = *(const f16x8*)(whhT_hi + boff + m * 32);
            bf_lo[m] = *(const f16x8*)(whhT_lo + boff + m * 32);
        }
    }
    __syncthreads();

    for (int t = t0; t < t1; ++t) {
        // Pin B-fragments in VGPRs: "+v" makes them asm-defined each iter, so
        // the compiler cannot rematerialize them from whhT inside the loop.
        #pragma unroll
        for (int m = 0; m < 32; m += 4)
            asm volatile("" : "+v"(bf_hi[m]), "+v"(bf_hi[m+1]),
                              "+v"(bf_hi[m+2]), "+v"(bf_hi[m+3]),
                              "+v"(bf_lo[m]), "+v"(bf_lo[m+1]),
                              "+v"(bf_lo[m+2]), "+v"(bf_lo[m+3]));

        if (t > 0) {
            // wait for all 64 producers of h_t (step t-1): RELAXED polls
            unsigned* f = flags + (size_t)(t - 1) * NWG;
            while (!__all((int)(__hip_atomic_load(&f[lane], __ATOMIC_RELAXED,
                                                  __HIP_MEMORY_SCOPE_AGENT) != 0u)))
                __builtin_amdgcn_s_sleep(1);
            // one invalidate so the cached h loads below can't hit stale L1/L2
            __builtin_amdgcn_fence(__ATOMIC_ACQUIRE, "agent");
        }
        const _Float16* hin_hi  = hbuf + (size_t)( t      & 1) * HBUFSZ;
        const _Float16* hin_lo  = hin_hi + HPLANE;
        _Float16*       hout_hi = hbuf + (size_t)((t + 1) & 1) * HBUFSZ;
        _Float16*       hout_lo = hout_hi + HPLANE;

        // hoist token loads (independent of the MFMA chain)
        int tok[4];
        #pragma unroll
        for (int r = 0; r < 4; ++r)
            tok[r] = x[(size_t)(n0 + lq * 4 + r) * TSEQ + t];

        // 16x16 tile (n0..+15) x (j0..+15), K=1024, double-fp16:
        //   result = acc0 + acc1 * 2^-11
        f32x4 acc0 = {0.f, 0.f, 0.f, 0.f};
        f32x4 acc1 = {0.f, 0.f, 0.f, 0.f};
        const size_t aoff = (size_t)(n0 + lr) * HDIM + lq * 8;
        #pragma unroll
        for (int m = 0; m < 32; ++m) {
            f16x8 a_hi = *(const f16x8*)(hin_hi + aoff + m * 32);
            f16x8 a_lo = *(const f16x8*)(hin_lo + aoff + m * 32);
            acc0 = __builtin_amdgcn_mfma_f32_16x16x32_f16(a_hi, bf_hi[m], acc0, 0, 0, 0);
            acc1 = __builtin_amdgcn_mfma_f32_16x16x32_f16(a_lo, bf_hi[m], acc1, 0, 0, 0);
            acc1 = __builtin_amdgcn_mfma_f32_16x16x32_f16(a_hi, bf_lo[m], acc1, 0, 0, 0);
        }

        // epilogue: D layout row=(lq*4+r), col=lr
        _Float16* zrow = z + (size_t)(t - t0) * (NSEQ * HDIM);
        unsigned hb[4], lb[4];
        #pragma unroll
        for (int r = 0; r < 4; ++r) {
            int n = n0 + lq * 4 + r;
            int j = j0 + lr;
            float pre = acc0[r] + acc1[r] * LOINV + e_s[tok[r]][lr];
            float hv  = tanhf(pre);
            _Float16 h16 = (_Float16)hv;
            _Float16 l16 = (_Float16)((hv - (float)h16) * LOSCALE);
            union { _Float16 f; unsigned short u; } ch{h16}, cl{l16};
            hb[r] = ch.u; lb[r] = cl.u;
            zrow[(size_t)n * HDIM + j] = h16;                       // cached
            if (t == TSEQ - 1) hlast_out[(size_t)n * HDIM + j] = hv; // cached
        }
        // h exchange: bypass L1/L2 (sc0 sc1) so data is at L3 (agent coherence
        // point) once vmcnt(0) clears -> no wbl2 release fence needed.
        {
            const _Float16* ah0 = hout_hi + (size_t)(n0 + lq * 4) * HDIM + j0 + lr;
            const _Float16* ah2 = ah0 + 2 * HDIM;
            const _Float16* al0 = hout_lo + (size_t)(n0 + lq * 4) * HDIM + j0 + lr;
            const _Float16* al2 = al0 + 2 * HDIM;
            asm volatile(
                "global_store_short %[ah0], %[h0], off sc0 sc1\n\t"
                "global_store_short %[ah0], %[h1], off offset:2048 sc0 sc1\n\t"
                "global_store_short %[ah2], %[h2], off sc0 sc1\n\t"
                "global_store_short %[ah2], %[h3], off offset:2048 sc0 sc1\n\t"
                "global_store_short %[al0], %[l0], off sc0 sc1\n\t"
                "global_store_short %[al0], %[l1], off offset:2048 sc0 sc1\n\t"
                "global_store_short %[al2], %[l2], off sc0 sc1\n\t"
                "global_store_short %[al2], %[l3], off offset:2048 sc0 sc1\n\t"
                "s_waitcnt vmcnt(0)"
                :
                : [ah0]"v"(ah0), [ah2]"v"(ah2), [al0]"v"(al0), [al2]"v"(al2),
                  [h0]"v"(hb[0]), [h1]"v"(hb[1]), [h2]"v"(hb[2]), [h3]"v"(hb[3]),
                  [l0]"v"(lb[0]), [l1]"v"(lb[1]), [l2]"v"(lb[2]), [l3]"v"(lb[3])
                : "memory");
        }
        __syncthreads();      // all lanes of this WG have drained their stores
        if (tid == 0)
            __hip_atomic_store(&flags[(size_t)t * NWG + c], 1u,
                               __ATOMIC_RELAXED, __HIP_MEMORY_SCOPE_AGENT);
    }
}

// ---------------------------------------------------------------- output GEMM + softmax
__global__ __launch_bounds__(256, 1) void rnn_out(
    const _Float16* __restrict__ z,      // chunk: [tc][NSEQ*HDIM]
    const _Float16* __restrict__ woutT,  // [ODIM][HDIM]
    const float* __restrict__ bout,      // [ODIM]
    float* __restrict__ y,               // [NSEQ][TSEQ][ODIM]
    int t0, int tc)
{
    const int b = blockIdx.x;
    const int t_rel = b >> 2, ng = b & 3;
    const int t = t0 + t_rel;
    const int n0 = ng * 16;
    const int tid = threadIdx.x;
    const int lane = tid & 63, wv = tid >> 6;
    const int lr = lane & 15, lq = lane >> 4;

    __shared__ float lg[16][ODIM + 8];   // logits staging

    const _Float16* abase = z + (size_t)t_rel * (NSEQ * HDIM)
                              + (size_t)(n0 + lr) * HDIM + lq * 8;
    f16x8 af[32];
    #pragma unroll
    for (int m = 0; m < 32; ++m) af[m] = *(const f16x8*)(abase + m * 32);

    #pragma unroll
    for (int i = 0; i < 4; ++i) {
        int ot = (wv * 4 + i) * 16;
        const _Float16* bbase = woutT + (size_t)(ot + lr) * HDIM + lq * 8;
        f32x4 acc = {0.f, 0.f, 0.f, 0.f};
        #pragma unroll
        for (int m = 0; m < 32; ++m) {
            f16x8 bfr = *(const f16x8*)(bbase + m * 32);
            acc = __builtin_amdgcn_mfma_f32_16x16x32_f16(af[m], bfr, acc, 0, 0, 0);
        }
        #pragma unroll
        for (int r = 0; r < 4; ++r)
            lg[lq * 4 + r][ot + lr] = acc[r];
    }
    __syncthreads();

    for (int rr = 0; rr < 4; ++rr) {
        int row = wv * 4 + rr;
        int n = n0 + row;
        float v0 = lg[row][lane]       + bout[lane];
        float v1 = lg[row][64 + lane]  + bout[64 + lane];
        float v2 = lg[row][128 + lane] + bout[128 + lane];
        float v3 = lg[row][192 + lane] + bout[192 + lane];
        float mx = fmaxf(fmaxf(v0, v1), fmaxf(v2, v3));
        for (int s = 32; s > 0; s >>= 1) mx = fmaxf(mx, __shfl_xor(mx, s));
        float e0 = __expf(v0 - mx), e1 = __expf(v1 - mx);
        float e2 = __expf(v2 - mx), e3 = __expf(v3 - mx);
        float sm = e0 + e1 + e2 + e3;
        for (int s = 32; s > 0; s >>= 1) sm += __shfl_xor(sm, s);
        float inv = 1.f / sm;
        float* dst = y + ((size_t)n * TSEQ + t) * ODIM;
        dst[lane]       = e0 * inv;
        dst[64 + lane]  = e1 * inv;
        dst[128 + lane] = e2 * inv;
        dst[192 + lane] = e3 * inv;
    }
}

// ---------------------------------------------------------------- launch
extern "C" void kernel_launch(void* const* d_in, const int* in_sizes, int n_in,
                              void* d_out, int out_size, void* d_ws, size_t ws_size,
                              hipStream_t stream)
{
    const int*   x    = (const int*)  d_in[0];
    const float* E    = (const float*)d_in[1];
    const float* Whh  = (const float*)d_in[2];
    const float* bh   = (const float*)d_in[3];
    const float* Wout = (const float*)d_in[4];
    const float* bout = (const float*)d_in[5];

    float* y     = (float*)d_out;
    float* hlast = y + (size_t)NSEQ * TSEQ * ODIM;

    char* ws = (char*)d_ws;
    size_t off = 0;
    auto alloc = [&](size_t bytes) -> void* {
        void* p = ws + off;
        off = (off + bytes + 255) & ~(size_t)255;
        return p;
    };
    _Float16* whhT_hi = (_Float16*)alloc((size_t)HDIM * HDIM * 2);
    _Float16* whhT_lo = (_Float16*)alloc((size_t)HDIM * HDIM * 2);
    _Float16* woutT   = (_Float16*)alloc((size_t)ODIM * HDIM * 2);
    _Float16* hbuf    = (_Float16*)alloc((size_t)2 * HBUFSZ * 2);
    unsigned* flags   = (unsigned*)alloc((size_t)TSEQ * NWG * 4);
    _Float16* z       = (_Float16*)(ws + off);

    size_t zcap = (ws_size > off) ? (ws_size - off) : 0;
    int tc_max = (int)(zcap / ((size_t)NSEQ * HDIM * 2));
    if (tc_max > TSEQ) tc_max = TSEQ;
    if (tc_max < 1)    tc_max = 1;

    rnn_init<<<2048, 256, 0, stream>>>(Whh, Wout, whhT_hi, whhT_lo, woutT,
                                       hbuf, flags);

    for (int t0 = 0; t0 < TSEQ; t0 += tc_max) {
        int tc = TSEQ - t0 < tc_max ? TSEQ - t0 : tc_max;
        rnn_steps<<<NWG, 256, 0, stream>>>(x, E, bh, whhT_hi, whhT_lo, hbuf,
                                           flags, z, hlast, t0, t0 + tc);
        rnn_out<<<tc * 4, 256, 0, stream>>>(z, woutT, bout, y, t0, tc);
    }
}

// Round 6
// 12771.491 us; speedup vs baseline: 2.4431x; 1.4202x over previous
//
#include <hip/hip_runtime.h>

// RNN: h_t = tanh(E[x_t] + h_{t-1} @ Whh + bh), T=1024, N=64, H=1024.
// y = softmax(z @ Wout + bout). Output: y (64*1024*256 f32) then h_last (64*1024 f32).
//
// Double-FP16 recurrence (hi + 2^-11*lo of h and Whh) -> fp32-equivalent
// per-step precision (R3/R5: passed, absmax 9.8e-4).
// R6 changes (R5 was 17.4us/step = ~64 serialized L3 round trips: Whh frags
// spilled to scratch (VGPR=160, asm pin backfired) + per-m A loads waited
// individually after the per-step L2 invalidate):
//  - Whh hi/lo fragments live in LDS (64 KB): immune to the per-step acquire
//    invalidate, no VGPR residency needed, ds_read_b128 ~12cy pipelined
//  - A (h) stream deep-prefetched: 4 chunks x 8 m, double-buffered in regs
//    (all compile-time indices), ~16 loads in flight instead of 1
//  - asm pin removed

typedef _Float16 f16x8 __attribute__((ext_vector_type(8)));
typedef float    f32x4 __attribute__((ext_vector_type(4)));

#define NSEQ  64
#define TSEQ  1024
#define HDIM  1024
#define VOCABSZ 256
#define ODIM  256
#define NWG   64     // one WG per 16 columns of H
#define LOSCALE 2048.0f
#define LOINV  (1.0f/2048.0f)

// hbuf layout: [buf(2)][plane(2: hi,lo)][NSEQ][HDIM] fp16
#define HPLANE (NSEQ * HDIM)
#define HBUFSZ (2 * HPLANE)

// ---------------------------------------------------------------- init / prep
__global__ __launch_bounds__(256) void rnn_init(
    const float* __restrict__ Whh, const float* __restrict__ Wout,
    _Float16* __restrict__ whhT_hi, _Float16* __restrict__ whhT_lo,
    _Float16* __restrict__ woutT,
    _Float16* __restrict__ hbuf, unsigned* __restrict__ flags)
{
    int i = blockIdx.x * 256 + threadIdx.x;
    int stride = gridDim.x * 256;
    for (int idx = i; idx < HDIM * HDIM; idx += stride) {
        int j = idx >> 10, k = idx & 1023;
        float w = Whh[k * HDIM + j];
        _Float16 hi = (_Float16)w;
        whhT_hi[idx] = hi;
        whhT_lo[idx] = (_Float16)((w - (float)hi) * LOSCALE);
    }
    for (int idx = i; idx < ODIM * HDIM; idx += stride) {
        int o = idx >> 10, k = idx & 1023;
        woutT[idx] = (_Float16)Wout[k * ODIM + o];
    }
    for (int idx = i; idx < 2 * HBUFSZ; idx += stride) hbuf[idx] = (_Float16)0.f;
    for (int idx = i; idx < TSEQ * NWG; idx += stride) flags[idx] = 0u;
}

// ---------------------------------------------------------------- recurrence
__global__ __launch_bounds__(256, 1) void rnn_steps(
    const int*   __restrict__ x,          // [NSEQ][TSEQ]
    const float* __restrict__ E,          // [VOCAB][HDIM]
    const float* __restrict__ bh,         // [HDIM]
    const _Float16* __restrict__ whhT_hi, // [HDIM][HDIM] j-major
    const _Float16* __restrict__ whhT_lo,
    _Float16* __restrict__ hbuf,
    unsigned* __restrict__ flags,         // [TSEQ][NWG]
    _Float16* __restrict__ z,             // chunk: [tc][NSEQ*HDIM]
    float* __restrict__ hlast_out,        // [NSEQ*HDIM]
    int t0, int t1)
{
    const int c   = blockIdx.x;        // column-group 0..63
    const int j0  = c * 16;
    const int tid = threadIdx.x;
    const int lane = tid & 63;
    const int wv   = tid >> 6;         // wave 0..3 -> seq rows n0..n0+15
    const int n0   = wv * 16;
    const int lr   = lane & 15;        // fragment row/col selector
    const int lq   = lane >> 4;        // k-chunk selector (0..3)

    __shared__ float e_s[VOCABSZ][16];        // (E + bh) slice, 16 KB
    __shared__ _Float16 bls[2][32][64][8];    // Whh^T hi/lo fragments, 64 KB

    {   // stage E[:, j0:j0+16] + bh fold
        const float* src = E + (size_t)tid * HDIM + j0;
        #pragma unroll
        for (int jj = 0; jj < 16; ++jj) e_s[tid][jj] = src[jj] + bh[j0 + jj];
    }
    if (wv == 0) {  // stage B fragments (identical for all waves) into LDS
        const size_t boff = (size_t)(j0 + lr) * HDIM + lq * 8;
        #pragma unroll
        for (int m = 0; m < 32; ++m) {
            *(f16x8*)&bls[0][m][lane][0] = *(const f16x8*)(whhT_hi + boff + m * 32);
            *(f16x8*)&bls[1][m][lane][0] = *(const f16x8*)(whhT_lo + boff + m * 32);
        }
    }
    __syncthreads();

    for (int t = t0; t < t1; ++t) {
        if (t > 0) {
            // wait for all 64 producers of h_t (step t-1): RELAXED polls
            unsigned* f = flags + (size_t)(t - 1) * NWG;
            while (!__all((int)(__hip_atomic_load(&f[lane], __ATOMIC_RELAXED,
                                                  __HIP_MEMORY_SCOPE_AGENT) != 0u)))
                __builtin_amdgcn_s_sleep(1);
            // one invalidate so cached h loads below can't hit stale L1/L2
            __builtin_amdgcn_fence(__ATOMIC_ACQUIRE, "agent");
        }
        const _Float16* hin_hi  = hbuf + (size_t)( t      & 1) * HBUFSZ;
        const _Float16* hin_lo  = hin_hi + HPLANE;
        _Float16*       hout_hi = hbuf + (size_t)((t + 1) & 1) * HBUFSZ;
        _Float16*       hout_lo = hout_hi + HPLANE;

        // hoist token loads (independent of the MFMA chain)
        int tok[4];
        #pragma unroll
        for (int r = 0; r < 4; ++r)
            tok[r] = x[(size_t)(n0 + lq * 4 + r) * TSEQ + t];

        // 16x16 tile (n0..+15) x (j0..+15), K=1024, double-fp16:
        //   result = acc0 + acc1 * 2^-11
        // A stream: 4 chunks of 8 m, double-buffered register prefetch
        // (indices all compile-time -> stays in VGPRs, rule #20).
        f32x4 acc0 = {0.f, 0.f, 0.f, 0.f};
        f32x4 acc1 = {0.f, 0.f, 0.f, 0.f};
        const _Float16* Ah = hin_hi + (size_t)(n0 + lr) * HDIM + lq * 8;
        const _Float16* Al = hin_lo + (size_t)(n0 + lr) * HDIM + lq * 8;

        f16x8 pah[2][8], pal[2][8];
        #pragma unroll
        for (int i = 0; i < 8; ++i) {
            pah[0][i] = *(const f16x8*)(Ah + i * 32);
            pal[0][i] = *(const f16x8*)(Al + i * 32);
        }
        #pragma unroll
        for (int ch = 0; ch < 4; ++ch) {
            const int cb = ch & 1, nb = cb ^ 1;
            if (ch < 3) {
                #pragma unroll
                for (int i = 0; i < 8; ++i) {
                    const int m = (ch + 1) * 8 + i;
                    pah[nb][i] = *(const f16x8*)(Ah + m * 32);
                    pal[nb][i] = *(const f16x8*)(Al + m * 32);
                }
            }
            #pragma unroll
            for (int i = 0; i < 8; ++i) {
                const int m = ch * 8 + i;
                f16x8 bhv = *(const f16x8*)&bls[0][m][lane][0];
                f16x8 blv = *(const f16x8*)&bls[1][m][lane][0];
                acc0 = __builtin_amdgcn_mfma_f32_16x16x32_f16(pah[cb][i], bhv, acc0, 0, 0, 0);
                acc1 = __builtin_amdgcn_mfma_f32_16x16x32_f16(pal[cb][i], bhv, acc1, 0, 0, 0);
                acc1 = __builtin_amdgcn_mfma_f32_16x16x32_f16(pah[cb][i], blv, acc1, 0, 0, 0);
            }
        }

        // epilogue: D layout row=(lq*4+r), col=lr
        _Float16* zrow = z + (size_t)(t - t0) * (NSEQ * HDIM);
        unsigned hb[4], lb[4];
        #pragma unroll
        for (int r = 0; r < 4; ++r) {
            int n = n0 + lq * 4 + r;
            int j = j0 + lr;
            float pre = acc0[r] + acc1[r] * LOINV + e_s[tok[r]][lr];
            float hv  = tanhf(pre);
            _Float16 h16 = (_Float16)hv;
            _Float16 l16 = (_Float16)((hv - (float)h16) * LOSCALE);
            union { _Float16 f; unsigned short u; } ch{h16}, cl{l16};
            hb[r] = ch.u; lb[r] = cl.u;
            zrow[(size_t)n * HDIM + j] = h16;                        // cached
            if (t == TSEQ - 1) hlast_out[(size_t)n * HDIM + j] = hv; // cached
        }
        // h exchange: bypass L1/L2 (sc0 sc1) so data is at the agent coherence
        // point once vmcnt(0) clears -> no release fence needed.
        {
            const _Float16* ah0 = hout_hi + (size_t)(n0 + lq * 4) * HDIM + j0 + lr;
            const _Float16* ah2 = ah0 + 2 * HDIM;
            const _Float16* al0 = hout_lo + (size_t)(n0 + lq * 4) * HDIM + j0 + lr;
            const _Float16* al2 = al0 + 2 * HDIM;
            asm volatile(
                "global_store_short %[ah0], %[h0], off sc0 sc1\n\t"
                "global_store_short %[ah0], %[h1], off offset:2048 sc0 sc1\n\t"
                "global_store_short %[ah2], %[h2], off sc0 sc1\n\t"
                "global_store_short %[ah2], %[h3], off offset:2048 sc0 sc1\n\t"
                "global_store_short %[al0], %[l0], off sc0 sc1\n\t"
                "global_store_short %[al0], %[l1], off offset:2048 sc0 sc1\n\t"
                "global_store_short %[al2], %[l2], off sc0 sc1\n\t"
                "global_store_short %[al2], %[l3], off offset:2048 sc0 sc1\n\t"
                "s_waitcnt vmcnt(0)"
                :
                : [ah0]"v"(ah0), [ah2]"v"(ah2), [al0]"v"(al0), [al2]"v"(al2),
                  [h0]"v"(hb[0]), [h1]"v"(hb[1]), [h2]"v"(hb[2]), [h3]"v"(hb[3]),
                  [l0]"v"(lb[0]), [l1]"v"(lb[1]), [l2]"v"(lb[2]), [l3]"v"(lb[3])
                : "memory");
        }
        __syncthreads();      // all lanes of this WG have drained their stores
        if (tid == 0)
            __hip_atomic_store(&flags[(size_t)t * NWG + c], 1u,
                               __ATOMIC_RELAXED, __HIP_MEMORY_SCOPE_AGENT);
    }
}

// ---------------------------------------------------------------- output GEMM + softmax
__global__ __launch_bounds__(256, 1) void rnn_out(
    const _Float16* __restrict__ z,      // chunk: [tc][NSEQ*HDIM]
    const _Float16* __restrict__ woutT,  // [ODIM][HDIM]
    const float* __restrict__ bout,      // [ODIM]
    float* __restrict__ y,               // [NSEQ][TSEQ][ODIM]
    int t0, int tc)
{
    const int b = blockIdx.x;
    const int t_rel = b >> 2, ng = b & 3;
    const int t = t0 + t_rel;
    const int n0 = ng * 16;
    const int tid = threadIdx.x;
    const int lane = tid & 63, wv = tid >> 6;
    const int lr = lane & 15, lq = lane >> 4;

    __shared__ float lg[16][ODIM + 8];   // logits staging

    const _Float16* abase = z + (size_t)t_rel * (NSEQ * HDIM)
                              + (size_t)(n0 + lr) * HDIM + lq * 8;
    f16x8 af[32];
    #pragma unroll
    for (int m = 0; m < 32; ++m) af[m] = *(const f16x8*)(abase + m * 32);

    #pragma unroll
    for (int i = 0; i < 4; ++i) {
        int ot = (wv * 4 + i) * 16;
        const _Float16* bbase = woutT + (size_t)(ot + lr) * HDIM + lq * 8;
        f32x4 acc = {0.f, 0.f, 0.f, 0.f};
        #pragma unroll
        for (int m = 0; m < 32; ++m) {
            f16x8 bfr = *(const f16x8*)(bbase + m * 32);
            acc = __builtin_amdgcn_mfma_f32_16x16x32_f16(af[m], bfr, acc, 0, 0, 0);
        }
        #pragma unroll
        for (int r = 0; r < 4; ++r)
            lg[lq * 4 + r][ot + lr] = acc[r];
    }
    __syncthreads();

    for (int rr = 0; rr < 4; ++rr) {
        int row = wv * 4 + rr;
        int n = n0 + row;
        float v0 = lg[row][lane]       + bout[lane];
        float v1 = lg[row][64 + lane]  + bout[64 + lane];
        float v2 = lg[row][128 + lane] + bout[128 + lane];
        float v3 = lg[row][192 + lane] + bout[192 + lane];
        float mx = fmaxf(fmaxf(v0, v1), fmaxf(v2, v3));
        for (int s = 32; s > 0; s >>= 1) mx = fmaxf(mx, __shfl_xor(mx, s));
        float e0 = __expf(v0 - mx), e1 = __expf(v1 - mx);
        float e2 = __expf(v2 - mx), e3 = __expf(v3 - mx);
        float sm = e0 + e1 + e2 + e3;
        for (int s = 32; s > 0; s >>= 1) sm += __shfl_xor(sm, s);
        float inv = 1.f / sm;
        float* dst = y + ((size_t)n * TSEQ + t) * ODIM;
        dst[lane]       = e0 * inv;
        dst[64 + lane]  = e1 * inv;
        dst[128 + lane] = e2 * inv;
        dst[192 + lane] = e3 * inv;
    }
}

// ---------------------------------------------------------------- launch
extern "C" void kernel_launch(void* const* d_in, const int* in_sizes, int n_in,
                              void* d_out, int out_size, void* d_ws, size_t ws_size,
                              hipStream_t stream)
{
    const int*   x    = (const int*)  d_in[0];
    const float* E    = (const float*)d_in[1];
    const float* Whh  = (const float*)d_in[2];
    const float* bh   = (const float*)d_in[3];
    const float* Wout = (const float*)d_in[4];
    const float* bout = (const float*)d_in[5];

    float* y     = (float*)d_out;
    float* hlast = y + (size_t)NSEQ * TSEQ * ODIM;

    char* ws = (char*)d_ws;
    size_t off = 0;
    auto alloc = [&](size_t bytes) -> void* {
        void* p = ws + off;
        off = (off + bytes + 255) & ~(size_t)255;
        return p;
    };
    _Float16* whhT_hi = (_Float16*)alloc((size_t)HDIM * HDIM * 2);
    _Float16* whhT_lo = (_Float16*)alloc((size_t)HDIM * HDIM * 2);
    _Float16* woutT   = (_Float16*)alloc((size_t)ODIM * HDIM * 2);
    _Float16* hbuf    = (_Float16*)alloc((size_t)2 * HBUFSZ * 2);
    unsigned* flags   = (unsigned*)alloc((size_t)TSEQ * NWG * 4);
    _Float16* z       = (_Float16*)(ws + off);

    size_t zcap = (ws_size > off) ? (ws_size - off) : 0;
    int tc_max = (int)(zcap / ((size_t)NSEQ * HDIM * 2));
    if (tc_max > TSEQ) tc_max = TSEQ;
    if (tc_max < 1)    tc_max = 1;

    rnn_init<<<2048, 256, 0, stream>>>(Whh, Wout, whhT_hi, whhT_lo, woutT,
                                       hbuf, flags);

    for (int t0 = 0; t0 < TSEQ; t0 += tc_max) {
        int tc = TSEQ - t0 < tc_max ? TSEQ - t0 : tc_max;
        rnn_steps<<<NWG, 256, 0, stream>>>(x, E, bh, whhT_hi, whhT_lo, hbuf,
                                           flags, z, hlast, t0, t0 + tc);
        rnn_out<<<tc * 4, 256, 0, stream>>>(z, woutT, bout, y, t0, tc);
    }
}